// Round 8
// baseline (290.177 us; speedup 1.0000x reference)
//
#include <hip/hip_runtime.h>
#include <hip/hip_fp16.h>

#define N_NODES 40000
#define N_EDGES 640000
#define NFEAT   128
#define N_GRAPHS 512
#define SCAN_NB 157        // ceil(40000/256)
#define NBKT    157        // col buckets of 256 cols
#define BKT_CAP 8192       // slots per bucket region (mean ~4076, safe)
#define BIN_BLK_EDGES 2048
#define NBLK_A ((N_EDGES + BIN_BLK_EDGES - 1) / BIN_BLK_EDGES)  // 313
#define EPAD_MAX (N_EDGES + 3 * N_NODES)   // worst-case pad-4 CSR = 760000 < 2^20

// ===========================================================================
// Init: gcursor=0 (incl. gbase slot), gcnt=0, out=bfc, both sentinel rows=0
// ===========================================================================
__global__ void init_misc_kernel(int* __restrict__ gcursor, int* __restrict__ gcnt,
                                 float* __restrict__ out, const float* __restrict__ bfc,
                                 __half* __restrict__ hsent1, __half* __restrict__ hsent2) {
    int t = threadIdx.x;
    if (t <= NBKT) gcursor[t] = 0;          // [NBKT] is the global CSR base cursor
    float b = bfc[0];
    for (int i = t; i < N_GRAPHS; i += 256) { gcnt[i] = 0; out[i] = b; }
    if (t < NFEAT) { hsent1[t] = __float2half(0.0f); hsent2[t] = __float2half(0.0f); }
}

__global__ void batch_hist_kernel(const int* __restrict__ batch, int* __restrict__ gcnt, int n) {
    int i = blockIdx.x * blockDim.x + threadIdx.x;
    if (i < n) atomicAdd(&gcnt[batch[i]], 1);
}

// ===========================================================================
// Pass A: bin edges into NBKT coarse buckets (col>>8), packed (collow<<16|row).
// ===========================================================================
__global__ __launch_bounds__(256) void bin_kernel(const int* __restrict__ ei,
                                                  int* __restrict__ gcursor,
                                                  unsigned int* __restrict__ binned) {
    __shared__ int lhist[NBKT];
    __shared__ int lbase[NBKT];
    const int t  = threadIdx.x;
    const int e0 = blockIdx.x * BIN_BLK_EDGES;

    if (t < NBKT) lhist[t] = 0;
    __syncthreads();

    int creg[BIN_BLK_EDGES / 256];
    #pragma unroll
    for (int i = 0; i < BIN_BLK_EDGES / 256; ++i) {
        int e = e0 + i * 256 + t;
        creg[i] = (e < N_EDGES) ? ei[N_EDGES + e] : -1;
        if (creg[i] >= 0) atomicAdd(&lhist[creg[i] >> 8], 1);
    }
    __syncthreads();

    if (t < NBKT) { lbase[t] = atomicAdd(&gcursor[t], lhist[t]); lhist[t] = 0; }
    __syncthreads();

    #pragma unroll
    for (int i = 0; i < BIN_BLK_EDGES / 256; ++i) {
        int c = creg[i];
        if (c >= 0) {
            int e = e0 + i * 256 + t;
            int r = ei[e];
            int bkt = c >> 8;
            int slot = atomicAdd(&lhist[bkt], 1);
            binned[(size_t)bkt * BKT_CAP + lbase[bkt] + slot] =
                (unsigned int)r | ((unsigned int)(c & 255) << 16);
        }
    }
}

// ===========================================================================
// Pass B: per-bucket col histogram -> dinv, local scan of PAD-4 degrees, ONE
// global atomicAdd for the bucket base. rowptr[col] = start | (pd/4)<<20.
// Then scatter into CSR via LDS cursors and write sentinel pads.
// ===========================================================================
template <typename IdxT>
__global__ __launch_bounds__(256) void bucket_build_kernel(const unsigned int* __restrict__ binned,
                                                           const int* __restrict__ gcursor,
                                                           int* __restrict__ gbase,
                                                           float* __restrict__ dinv,
                                                           int* __restrict__ rowptr,
                                                           IdxT* __restrict__ csr) {
    __shared__ int chist[256];
    __shared__ int scn[256];
    __shared__ int ccur[256];
    __shared__ int sbase;
    const int b = blockIdx.x, t = threadIdx.x;
    chist[t] = 0;
    __syncthreads();
    const int cnt = gcursor[b];
    const unsigned int* src = binned + (size_t)b * BKT_CAP;
    for (int i = t; i < cnt; i += 256) atomicAdd(&chist[src[i] >> 16], 1);
    __syncthreads();
    const int col = b * 256 + t;
    const int valid = (col < N_NODES);
    int d = chist[t];
    if (valid) dinv[col] = rsqrtf(1.0f + (float)d);
    int pd = valid ? ((d + 3) & ~3) : 0;
    scn[t] = pd;
    __syncthreads();
    for (int off = 1; off < 256; off <<= 1) {
        int add = (t >= off) ? scn[t - off] : 0;
        __syncthreads();
        scn[t] += add;
        __syncthreads();
    }
    if (t == 255) sbase = atomicAdd(gbase, scn[255]);
    __syncthreads();
    const int start = sbase + scn[t] - pd;
    if (valid) rowptr[col] = start | ((pd >> 2) << 20);
    ccur[t] = start;
    __syncthreads();
    for (int i = t; i < cnt; i += 256) {
        unsigned int u = src[i];
        int slot = atomicAdd(&ccur[u >> 16], 1);
        csr[slot] = (IdxT)(u & 0xFFFFu);
    }
    __syncthreads();
    if (valid) {
        int cur = ccur[t];
        int endp = start + pd;
        for (int p = cur; p < endp; ++p) csr[p] = (IdxT)N_NODES;
    }
}

// ===========================================================================
// fp16 load helper
// ===========================================================================
__device__ inline float4 load_h4(const __half* p) {
    uint2 raw = *(const uint2*)p;
    __half2 h0 = *(__half2*)&raw.x;
    __half2 h1 = *(__half2*)&raw.y;
    float2 f0 = __half22float2(h0);
    float2 f1 = __half22float2(h1);
    return make_float4(f0.x, f0.y, f1.x, f1.y);
}
__device__ inline float4 load4v(const float* p)  { return *(const float4*)(p); }
__device__ inline float4 load4v(const __half* p) { return load_h4(p); }

// ===========================================================================
// GEMM layer-1 (r9-proven shape): Ht[r][c] = dinv[r] * sum_k X[r][k] * W[k][c]
// 256 threads -> 64 rows x 64 cols, thread = 4x4; W col-half (32 KB LDS)
// -> 4 blocks/CU; explicit X double-buffer prefetch. fp16 out.
// ===========================================================================
template <typename InT>
__global__ __launch_bounds__(256, 4) void gemm64h_kernel(const InT* __restrict__ X,
                                                         const float* __restrict__ W,
                                                         const float* __restrict__ dinv,
                                                         __half* __restrict__ H) {
    __shared__ float Ws[128 * 64];
    const int colhalf = blockIdx.x & 1;
    const int tile    = blockIdx.x >> 1;

    for (int i = threadIdx.x; i < 2048; i += 256) {
        int k   = i >> 4;
        int cc4 = (i & 15) * 4;
        *(float4*)(Ws + k * 64 + cc4) = *(const float4*)(W + k * 128 + colhalf * 64 + cc4);
    }
    __syncthreads();

    const int rg = threadIdx.x >> 4;
    const int cg = threadIdx.x & 15;
    const int row0 = tile * 64 + rg * 4;
    const InT* x0 = X + (size_t)row0 * NFEAT;

    float acc[4][4] = {};
    float4 xc[4], xn[4];
    #pragma unroll
    for (int i = 0; i < 4; i++) xc[i] = load4v(x0 + (size_t)i * NFEAT);

    #pragma unroll 4
    for (int k = 0; k < 128; k += 4) {
        const int kn = (k + 4) & 127;
        #pragma unroll
        for (int i = 0; i < 4; i++) xn[i] = load4v(x0 + (size_t)i * NFEAT + kn);

        float4 wv[4];
        #pragma unroll
        for (int m = 0; m < 4; m++) wv[m] = *(const float4*)(Ws + (k + m) * 64 + cg * 4);

        #pragma unroll
        for (int i = 0; i < 4; i++) {
            const float xi[4] = {xc[i].x, xc[i].y, xc[i].z, xc[i].w};
            #pragma unroll
            for (int m = 0; m < 4; m++) {
                acc[i][0] += xi[m] * wv[m].x;
                acc[i][1] += xi[m] * wv[m].y;
                acc[i][2] += xi[m] * wv[m].z;
                acc[i][3] += xi[m] * wv[m].w;
            }
        }
        #pragma unroll
        for (int i = 0; i < 4; i++) xc[i] = xn[i];
    }

    #pragma unroll
    for (int i = 0; i < 4; i++) {
        float dr = dinv[row0 + i];
        __half2 p0 = __floats2half2_rn(acc[i][0] * dr, acc[i][1] * dr);
        __half2 p1 = __floats2half2_rn(acc[i][2] * dr, acc[i][3] * dr);
        uint2 pk;
        pk.x = *(unsigned int*)&p0;
        pk.y = *(unsigned int*)&p1;
        *(uint2*)(H + (size_t)(row0 + i) * NFEAT + colhalf * 64 + cg * 4) = pk;
    }
}

// ===========================================================================
// FUSED gather1 + gemm2: block = 256 threads, owns 64 nodes (grid 625).
// Phase 1: each wave gathers 16 node rows (r0-proven h16 routine: half-waves
// take alternating neighbors, 8 B/lane, padded-4 CSR, idx prefetch) and
// writes relu(bias + dinv*sum) as fp16 into LDS Xs[64][132] (pad kills bank
// conflicts). Phase 2: 64x128 GEMM vs W2 (col-half staged, 32 KB), output
// scaled by dinv -> hbuf2 (separate buffer: hbuf still being read by other
// blocks' gathers). GEMM VALU work hides under the sector-throughput-capped
// gather across co-resident blocks (3/CU: 49.7 KB LDS).
// ===========================================================================
template <typename IdxT, typename IdxV>
__global__ __launch_bounds__(256, 3) void gather_gemm_kernel(
        const int* __restrict__ rowptr, const IdxT* __restrict__ csr,
        const float* __restrict__ dinv, const __half* __restrict__ Ht,
        const float* __restrict__ bias, const float* __restrict__ W2,
        __half* __restrict__ H2) {
    __shared__ __half Xs[64][132];
    __shared__ float Ws[128 * 64];
    const int t    = threadIdx.x;
    const int wv   = t >> 6;
    const int lane = t & 63;
    const int half = lane >> 5;
    const int f4   = (lane & 31) * 4;
    const int nbase = blockIdx.x * 64;

    // stage W2 col-half 0 early — the loads land while gathers stall
    for (int i = t; i < 2048; i += 256) {
        int k = i >> 4, cc4 = (i & 15) * 4;
        *(float4*)(Ws + k * 64 + cc4) = *(const float4*)(W2 + k * 128 + cc4);
    }

    // ---- phase 1: gather 16 nodes per wave into Xs ----
    for (int i = 0; i < 16; ++i) {
        const int nr   = wv * 16 + i;
        const int node = nbase + nr;
        unsigned int u = (unsigned int)rowptr[node];
        int start = (int)(u & 0xFFFFFu);
        int pd    = (int)(u >> 20) << 2;
        int end   = start + pd;

        float4 a0 = {0.f, 0.f, 0.f, 0.f};
        float4 a1 = {0.f, 0.f, 0.f, 0.f};
        if (half == 0) a0 = load_h4(Ht + (size_t)node * NFEAT + f4);  // self-loop

        if (start < end) {
            IdxV nxt = *(const IdxV*)(csr + start);
            for (int j = start; j < end; j += 4) {
                IdxV cur = nxt;
                int jn = j + 4;
                if (jn < end) nxt = *(const IdxV*)(csr + jn);
                int r0 = half ? (int)cur.z : (int)cur.x;
                int r1 = half ? (int)cur.w : (int)cur.y;
                float4 v0 = load_h4(Ht + (size_t)r0 * NFEAT + f4);
                float4 v1 = load_h4(Ht + (size_t)r1 * NFEAT + f4);
                a0.x += v0.x; a0.y += v0.y; a0.z += v0.z; a0.w += v0.w;
                a1.x += v1.x; a1.y += v1.y; a1.z += v1.z; a1.w += v1.w;
            }
        }
        a0.x += a1.x; a0.y += a1.y; a0.z += a1.z; a0.w += a1.w;

        a0.x += __shfl_xor(a0.x, 32, 64);
        a0.y += __shfl_xor(a0.y, 32, 64);
        a0.z += __shfl_xor(a0.z, 32, 64);
        a0.w += __shfl_xor(a0.w, 32, 64);

        if (half == 0) {
            float di  = dinv[node];
            float4 bb = *(const float4*)(bias + f4);
            float o0 = fmaxf(a0.x * di + bb.x, 0.0f);
            float o1 = fmaxf(a0.y * di + bb.y, 0.0f);
            float o2 = fmaxf(a0.z * di + bb.z, 0.0f);
            float o3 = fmaxf(a0.w * di + bb.w, 0.0f);
            __half2 p0 = __floats2half2_rn(o0, o1);
            __half2 p1 = __floats2half2_rn(o2, o3);
            uint2 pk;
            pk.x = *(unsigned int*)&p0;
            pk.y = *(unsigned int*)&p1;
            *(uint2*)&Xs[nr][f4] = pk;
        }
    }
    __syncthreads();   // Xs complete, Ws(half 0) complete

    // ---- phase 2: 64x128 GEMM from Xs, two column halves ----
    const int rg  = t >> 4;
    const int cg  = t & 15;
    const int r0g = rg * 4;
    #pragma unroll
    for (int ch = 0; ch < 2; ++ch) {
        if (ch == 1) {
            __syncthreads();   // everyone done reading Ws(half 0)
            for (int i = t; i < 2048; i += 256) {
                int k = i >> 4, cc4 = (i & 15) * 4;
                *(float4*)(Ws + k * 64 + cc4) = *(const float4*)(W2 + k * 128 + 64 + cc4);
            }
            __syncthreads();
        }
        float acc[4][4] = {};
        #pragma unroll 4
        for (int k = 0; k < 128; k += 4) {
            float4 xv[4], wvv[4];
            #pragma unroll
            for (int i = 0; i < 4; i++) xv[i] = load_h4(&Xs[r0g + i][k]);
            #pragma unroll
            for (int m = 0; m < 4; m++) wvv[m] = *(const float4*)(Ws + (k + m) * 64 + cg * 4);
            #pragma unroll
            for (int i = 0; i < 4; i++) {
                const float xi[4] = {xv[i].x, xv[i].y, xv[i].z, xv[i].w};
                #pragma unroll
                for (int m = 0; m < 4; m++) {
                    acc[i][0] += xi[m] * wvv[m].x;
                    acc[i][1] += xi[m] * wvv[m].y;
                    acc[i][2] += xi[m] * wvv[m].z;
                    acc[i][3] += xi[m] * wvv[m].w;
                }
            }
        }
        #pragma unroll
        for (int i = 0; i < 4; i++) {
            float dr = dinv[nbase + r0g + i];
            __half2 p0 = __floats2half2_rn(acc[i][0] * dr, acc[i][1] * dr);
            __half2 p1 = __floats2half2_rn(acc[i][2] * dr, acc[i][3] * dr);
            uint2 pk;
            pk.x = *(unsigned int*)&p0;
            pk.y = *(unsigned int*)&p1;
            *(uint2*)(H2 + (size_t)(nbase + r0g + i) * NFEAT + ch * 64 + cg * 4) = pk;
        }
    }
}

// ===========================================================================
// fp16 gather (r0-proven): one wave per node; 8 B/lane; half-waves take
// alternating neighbors; padded CSR -> aligned 4-index loads, next idx
// prefetched. FUSE_POOL: dot Wfc, reduce, store nodedot[node].
// ===========================================================================
template <typename IdxT, typename IdxV, bool FUSE_POOL>
__global__ __launch_bounds__(256) void gather_h16_kernel(
        const int* __restrict__ rowptr, const IdxT* __restrict__ csr,
        const float* __restrict__ dinv, const __half* __restrict__ Ht,
        const float* __restrict__ bias, __half* __restrict__ outh,
        const float* __restrict__ Wfc, float* __restrict__ nodedot, int n) {
    int gid  = blockIdx.x * blockDim.x + threadIdx.x;
    int node = gid >> 6;
    if (node >= n) return;
    int lane = threadIdx.x & 63;
    int half = lane >> 5;
    int f4   = (lane & 31) * 4;

    unsigned int u = (unsigned int)rowptr[node];
    int start = (int)(u & 0xFFFFFu);
    int pd    = (int)(u >> 20) << 2;
    int end   = start + pd;

    float4 a0 = {0.f, 0.f, 0.f, 0.f};
    float4 a1 = {0.f, 0.f, 0.f, 0.f};
    if (half == 0) a0 = load_h4(Ht + (size_t)node * NFEAT + f4);  // self-loop

    if (start < end) {
        IdxV nxt = *(const IdxV*)(csr + start);
        for (int j = start; j < end; j += 4) {
            IdxV cur = nxt;
            int jn = j + 4;
            if (jn < end) nxt = *(const IdxV*)(csr + jn);
            int r0 = half ? (int)cur.z : (int)cur.x;
            int r1 = half ? (int)cur.w : (int)cur.y;
            float4 v0 = load_h4(Ht + (size_t)r0 * NFEAT + f4);
            float4 v1 = load_h4(Ht + (size_t)r1 * NFEAT + f4);
            a0.x += v0.x; a0.y += v0.y; a0.z += v0.z; a0.w += v0.w;
            a1.x += v1.x; a1.y += v1.y; a1.z += v1.z; a1.w += v1.w;
        }
    }
    a0.x += a1.x; a0.y += a1.y; a0.z += a1.z; a0.w += a1.w;

    a0.x += __shfl_xor(a0.x, 32, 64);
    a0.y += __shfl_xor(a0.y, 32, 64);
    a0.z += __shfl_xor(a0.z, 32, 64);
    a0.w += __shfl_xor(a0.w, 32, 64);

    if (half == 0) {
        float di  = dinv[node];
        float4 bb = *(const float4*)(bias + f4);
        float4 o;
        o.x = fmaxf(a0.x * di + bb.x, 0.0f);
        o.y = fmaxf(a0.y * di + bb.y, 0.0f);
        o.z = fmaxf(a0.z * di + bb.z, 0.0f);
        o.w = fmaxf(a0.w * di + bb.w, 0.0f);
        if (!FUSE_POOL) {
            __half2 p0 = __floats2half2_rn(o.x, o.y);
            __half2 p1 = __floats2half2_rn(o.z, o.w);
            uint2 pk;
            pk.x = *(unsigned int*)&p0;
            pk.y = *(unsigned int*)&p1;
            *(uint2*)(outh + (size_t)node * NFEAT + f4) = pk;
        } else {
            float4 wf = *(const float4*)(Wfc + f4);
            float d = o.x * wf.x + o.y * wf.y + o.z * wf.z + o.w * wf.w;
            d += __shfl_xor(d, 1, 64);
            d += __shfl_xor(d, 2, 64);
            d += __shfl_xor(d, 4, 64);
            d += __shfl_xor(d, 8, 64);
            d += __shfl_xor(d, 16, 64);
            if (lane == 0) nodedot[node] = d;   // wave owns node: plain store
        }
    }
}

// out[batch[i]] += nodedot[i] / cnt
__global__ void pool_final_kernel(const float* __restrict__ nodedot,
                                  const int* __restrict__ batch,
                                  const int* __restrict__ gcnt,
                                  float* __restrict__ out, int n) {
    int i = blockIdx.x * blockDim.x + threadIdx.x;
    if (i < n) {
        int g = batch[i];
        int c = gcnt[g];
        float cf = (float)(c > 0 ? c : 1);
        atomicAdd(&out[g], nodedot[i] / cf);
    }
}

// ===========================================================================
// Tier C fallback kernels (fp32, atomic scatter)
// ===========================================================================
__global__ void edge_deg_int_kernel(const int* __restrict__ ei, int* __restrict__ degcnt, int E) {
    int e = blockIdx.x * blockDim.x + threadIdx.x;
    if (e < E) atomicAdd(&degcnt[ei[E + e]], 1);
}

__global__ void dinv_from_int_kernel(const int* __restrict__ degcnt, float* __restrict__ dinv, int n) {
    int i = blockIdx.x * blockDim.x + threadIdx.x;
    if (i < n) dinv[i] = rsqrtf(1.0f + (float)degcnt[i]);
}

__global__ __launch_bounds__(256, 4) void gemm64f_kernel(const float* __restrict__ X,
                                                         const float* __restrict__ W,
                                                         const float* __restrict__ dinv,
                                                         float* __restrict__ H) {
    __shared__ float Ws[128 * 64];
    const int colhalf = blockIdx.x & 1;
    const int tile    = blockIdx.x >> 1;
    for (int i = threadIdx.x; i < 2048; i += 256) {
        int k   = i >> 4;
        int cc4 = (i & 15) * 4;
        *(float4*)(Ws + k * 64 + cc4) = *(const float4*)(W + k * 128 + colhalf * 64 + cc4);
    }
    __syncthreads();
    const int rg = threadIdx.x >> 4;
    const int cg = threadIdx.x & 15;
    const int row0 = tile * 64 + rg * 4;
    const float* x0 = X + (size_t)row0 * NFEAT;
    float acc[4][4] = {};
    #pragma unroll 4
    for (int k = 0; k < 128; k += 4) {
        float4 xv[4];
        float4 wv[4];
        #pragma unroll
        for (int i = 0; i < 4; i++) xv[i] = *(const float4*)(x0 + (size_t)i * NFEAT + k);
        #pragma unroll
        for (int m = 0; m < 4; m++) wv[m] = *(const float4*)(Ws + (k + m) * 64 + cg * 4);
        #pragma unroll
        for (int i = 0; i < 4; i++) {
            const float xi[4] = {xv[i].x, xv[i].y, xv[i].z, xv[i].w};
            #pragma unroll
            for (int m = 0; m < 4; m++) {
                acc[i][0] += xi[m] * wv[m].x;
                acc[i][1] += xi[m] * wv[m].y;
                acc[i][2] += xi[m] * wv[m].z;
                acc[i][3] += xi[m] * wv[m].w;
            }
        }
    }
    #pragma unroll
    for (int i = 0; i < 4; i++) {
        float dr = dinv[row0 + i];
        float4 o = {acc[i][0] * dr, acc[i][1] * dr, acc[i][2] * dr, acc[i][3] * dr};
        *(float4*)(H + (size_t)(row0 + i) * NFEAT + cg * 4 + colhalf * 64) = o;
    }
}

__global__ __launch_bounds__(256) void edge_scatter_kernel(const int* __restrict__ ei,
                                                           const float* __restrict__ dinv,
                                                           const float* __restrict__ H,
                                                           float* __restrict__ agg,
                                                           int E) {
    long long gid = (long long)blockIdx.x * blockDim.x + threadIdx.x;
    int e = (int)(gid >> 5);
    if (e >= E) return;
    int c4 = ((int)gid & 31) * 4;
    int r = ei[e];
    int c = ei[E + e];
    float norm = dinv[c];
    const float4 hv = *(const float4*)(H + (size_t)r * NFEAT + c4);
    float* dst = agg + (size_t)c * NFEAT + c4;
    atomicAdd(dst + 0, hv.x * norm);
    atomicAdd(dst + 1, hv.y * norm);
    atomicAdd(dst + 2, hv.z * norm);
    atomicAdd(dst + 3, hv.w * norm);
}

__global__ void post_kernel(float* __restrict__ agg, const float* __restrict__ H,
                            const float* __restrict__ dinv, const float* __restrict__ b,
                            int n) {
    int gid = blockIdx.x * blockDim.x + threadIdx.x;
    if (gid >= n * 32) return;
    int node = gid >> 5;
    int c4 = (gid & 31) * 4;
    float s = dinv[node];
    float4 a  = *(float4*)(agg + (size_t)gid * 4);
    float4 hv = *(const float4*)(H + (size_t)gid * 4);
    float4 bb = *(const float4*)(b + c4);
    float4 o;
    o.x = fmaxf(a.x + hv.x * s + bb.x, 0.0f);
    o.y = fmaxf(a.y + hv.y * s + bb.y, 0.0f);
    o.z = fmaxf(a.z + hv.z * s + bb.z, 0.0f);
    o.w = fmaxf(a.w + hv.w * s + bb.w, 0.0f);
    *(float4*)(agg + (size_t)gid * 4) = o;
}

__global__ __launch_bounds__(128) void pool_fc_kernel(const float* __restrict__ H,
                                                      const int* __restrict__ batch,
                                                      const float* __restrict__ Wfc,
                                                      const float* __restrict__ bfc,
                                                      float* __restrict__ out, int n) {
    int g = blockIdx.x;
    int tid = threadIdx.x;
    int lo = 0, hi = n;
    while (lo < hi) { int mid = (lo + hi) >> 1; if (batch[mid] < g) lo = mid + 1; else hi = mid; }
    int start = lo;
    hi = n;
    while (lo < hi) { int mid = (lo + hi) >> 1; if (batch[mid] < g + 1) lo = mid + 1; else hi = mid; }
    int end = lo;
    float acc = 0.0f;
    for (int nd = start; nd < end; ++nd) acc += H[(size_t)nd * NFEAT + tid];
    float cnt = (float)((end - start) > 0 ? (end - start) : 1);
    float v = (acc / cnt) * Wfc[tid];
    __shared__ float red[128];
    red[tid] = v;
    __syncthreads();
    #pragma unroll
    for (int s = 64; s > 0; s >>= 1) {
        if (tid < s) red[tid] += red[tid + s];
        __syncthreads();
    }
    if (tid == 0) out[g] = red[0] + bfc[0];
}

// ===========================================================================
// Host launcher — main path: ushort CSR, fp16 hbuf + fp16 hbuf2, 8 dispatches
//   init -> batch_hist -> bin -> bucket_build -> gemm1 ->
//   FUSED(gather1+gemm2) -> gather2(nodedot) -> pool_final
// ===========================================================================
static void run_csr_path(const float* x, const int* ei, const int* batch,
                         const float* W1, const float* b1, const float* W2,
                         const float* b2, const float* Wfc, const float* bfc,
                         float* out, void* d_ws, hipStream_t stream) {
    typedef unsigned short IdxT;
    typedef ushort4 IdxV;
    char* ws = (char*)d_ws;
    const size_t hbytes = (size_t)(N_NODES + 1) * NFEAT * sizeof(__half);  // +1 sentinel row
    __half* hbuf  = (__half*)ws;
    __half* hbuf2 = (__half*)(ws + hbytes);
    IdxT*   csr   = (IdxT*)(ws + 2 * hbytes);
    char*   p     = ws + 2 * hbytes + ((size_t)EPAD_MAX * sizeof(IdxT) + 15) / 16 * 16;
    int*    rowptr = (int*)p;                p += ((size_t)(N_NODES + 1) * 4 + 15) / 16 * 16;
    float*  dinv   = (float*)p;              p += ((size_t)N_NODES * 4 + 15) / 16 * 16;
    int*    gcnt   = (int*)p;                // 512 ints (live through pool_final)
    float*  nodedot = (float*)(p + (((size_t)N_GRAPHS * 4 + 15) / 16 * 16));

    // CSR-build scratch overlapping hbuf2 (dead until fused kernel writes it)
    unsigned int* binned = (unsigned int*)hbuf2;       // NBKT*BKT_CAP u32 = 5.14 MB < 10.2 MB
    int* gcursor = (int*)(binned + (size_t)NBKT * BKT_CAP);  // NBKT+1 ints ([NBKT]=gbase)

    // ---- init + CSR build (binned counting sort, atomic bucket bases) ----
    init_misc_kernel<<<1, 256, 0, stream>>>(gcursor, gcnt, out, bfc,
                                            hbuf  + (size_t)N_NODES * NFEAT,
                                            hbuf2 + (size_t)N_NODES * NFEAT);
    batch_hist_kernel<<<SCAN_NB, 256, 0, stream>>>(batch, gcnt, N_NODES);
    bin_kernel<<<NBLK_A, 256, 0, stream>>>(ei, gcursor, binned);
    bucket_build_kernel<IdxT><<<NBKT, 256, 0, stream>>>(binned, gcursor, gcursor + NBKT,
                                                        dinv, rowptr, csr);

    // ---- layer 1 GEMM ----
    gemm64h_kernel<float><<<(N_NODES / 64) * 2, 256, 0, stream>>>(x, W1, dinv, hbuf);

    // ---- fused gather1 + gemm2 (hbuf -> LDS -> hbuf2) ----
    gather_gemm_kernel<IdxT, IdxV><<<N_NODES / 64, 256, 0, stream>>>(
        rowptr, csr, dinv, hbuf, b1, W2, hbuf2);

    // ---- gather2 (+Wfc dot -> nodedot), then pool ----
    gather_h16_kernel<IdxT, IdxV, true><<<(N_NODES * 64) / 256, 256, 0, stream>>>(
        rowptr, csr, dinv, hbuf2, b2, nullptr, Wfc, nodedot, N_NODES);
    pool_final_kernel<<<SCAN_NB, 256, 0, stream>>>(nodedot, batch, gcnt, out, N_NODES);
}

extern "C" void kernel_launch(void* const* d_in, const int* in_sizes, int n_in,
                              void* d_out, int out_size, void* d_ws, size_t ws_size,
                              hipStream_t stream) {
    const float* x     = (const float*)d_in[0];
    const int*   ei    = (const int*)  d_in[1];
    const int*   batch = (const int*)  d_in[2];
    const float* W1    = (const float*)d_in[3];
    const float* b1    = (const float*)d_in[4];
    const float* W2    = (const float*)d_in[5];
    const float* b2    = (const float*)d_in[6];
    const float* Wfc   = (const float*)d_in[7];
    const float* bfc   = (const float*)d_in[8];
    float* out = (float*)d_out;

    const size_t hbytes = (size_t)(N_NODES + 1) * NFEAT * sizeof(__half);
    const size_t tail   = ((size_t)(N_NODES + 1) * 4 + 15) / 16 * 16
                        + ((size_t)N_NODES * 4 + 15) / 16 * 16
                        + (((size_t)N_GRAPHS * 4 + 15) / 16 * 16)
                        + (size_t)N_NODES * 4;                       // nodedot
    const size_t need = 2 * hbytes + ((size_t)EPAD_MAX * 2 + 15) / 16 * 16 + tail;

    if (ws_size >= need) {
        run_csr_path(x, ei, batch, W1, b1, W2, b2, Wfc, bfc, out, d_ws, stream);
    } else {
        // Tier C: fp32 atomic-scatter fallback
        float* ws   = (float*)d_ws;
        int*   degc = (int*)ws;
        float* dinv = ws + N_NODES;
        float* hbuf = ws + 2 * N_NODES;
        float* agg  = hbuf + (size_t)N_NODES * NFEAT;
        const size_t fb2 = (size_t)N_NODES * NFEAT * sizeof(float);

        hipMemsetAsync(degc, 0, (size_t)N_NODES * sizeof(int), stream);
        edge_deg_int_kernel<<<N_EDGES / 256, 256, 0, stream>>>(ei, degc, N_EDGES);
        dinv_from_int_kernel<<<SCAN_NB, 256, 0, stream>>>(degc, dinv, N_NODES);

        hipMemsetAsync(agg, 0, fb2, stream);
        gemm64f_kernel<<<(N_NODES / 64) * 2, 256, 0, stream>>>(x, W1, dinv, hbuf);
        edge_scatter_kernel<<<(N_EDGES * 32) / 256, 256, 0, stream>>>(ei, dinv, hbuf, agg, N_EDGES);
        post_kernel<<<(N_NODES * 32) / 256, 256, 0, stream>>>(agg, hbuf, dinv, b1, N_NODES);

        gemm64f_kernel<<<(N_NODES / 64) * 2, 256, 0, stream>>>(agg, W2, dinv, hbuf);
        hipMemsetAsync(agg, 0, fb2, stream);
        edge_scatter_kernel<<<(N_EDGES * 32) / 256, 256, 0, stream>>>(ei, dinv, hbuf, agg, N_EDGES);
        post_kernel<<<(N_NODES * 32) / 256, 256, 0, stream>>>(agg, hbuf, dinv, b2, N_NODES);

        pool_fc_kernel<<<N_GRAPHS, 128, 0, stream>>>(agg, batch, Wfc, bfc, out, N_NODES);
    }
}

// Round 9
// 266.318 us; speedup vs baseline: 1.0896x; 1.0896x over previous
//
#include <hip/hip_runtime.h>
#include <hip/hip_fp16.h>

#define N_NODES 40000
#define N_EDGES 640000
#define NFEAT   128
#define N_GRAPHS 512
#define SCAN_NB 157        // ceil(40000/256)
#define NBKT    157        // col buckets of 256 cols
#define BKT_CAP 8192       // slots per bucket region (mean ~4076, safe)
#define BIN_BLK_EDGES 2048
#define NBLK_A ((N_EDGES + BIN_BLK_EDGES - 1) / BIN_BLK_EDGES)  // 313
#define EPAD_MAX (N_EDGES + 3 * N_NODES)   // worst-case padded CSR

// ===========================================================================
// Init: gcursor=0 (incl. gbase slot), gcnt=0, out=bfc, hbuf sentinel row=0
// ===========================================================================
__global__ void init_misc_kernel(int* __restrict__ gcursor, int* __restrict__ gcnt,
                                 float* __restrict__ out, const float* __restrict__ bfc,
                                 __half* __restrict__ hsent) {
    int t = threadIdx.x;
    if (t <= NBKT) gcursor[t] = 0;          // [NBKT] is the global CSR base cursor
    float b = bfc[0];
    for (int i = t; i < N_GRAPHS; i += 256) { gcnt[i] = 0; out[i] = b; }
    if (t < NFEAT) hsent[t] = __float2half(0.0f);
}

__global__ void batch_hist_kernel(const int* __restrict__ batch, int* __restrict__ gcnt, int n) {
    int i = blockIdx.x * blockDim.x + threadIdx.x;
    if (i < n) atomicAdd(&gcnt[batch[i]], 1);
}

// ===========================================================================
// Pass A: bin edges into NBKT coarse buckets (col>>8), packed (collow<<16|row).
// ===========================================================================
__global__ __launch_bounds__(256) void bin_kernel(const int* __restrict__ ei,
                                                  int* __restrict__ gcursor,
                                                  unsigned int* __restrict__ binned) {
    __shared__ int lhist[NBKT];
    __shared__ int lbase[NBKT];
    const int t  = threadIdx.x;
    const int e0 = blockIdx.x * BIN_BLK_EDGES;

    if (t < NBKT) lhist[t] = 0;
    __syncthreads();

    int creg[BIN_BLK_EDGES / 256];
    #pragma unroll
    for (int i = 0; i < BIN_BLK_EDGES / 256; ++i) {
        int e = e0 + i * 256 + t;
        creg[i] = (e < N_EDGES) ? ei[N_EDGES + e] : -1;
        if (creg[i] >= 0) atomicAdd(&lhist[creg[i] >> 8], 1);
    }
    __syncthreads();

    if (t < NBKT) { lbase[t] = atomicAdd(&gcursor[t], lhist[t]); lhist[t] = 0; }
    __syncthreads();

    #pragma unroll
    for (int i = 0; i < BIN_BLK_EDGES / 256; ++i) {
        int c = creg[i];
        if (c >= 0) {
            int e = e0 + i * 256 + t;
            int r = ei[e];
            int bkt = c >> 8;
            int slot = atomicAdd(&lhist[bkt], 1);
            binned[(size_t)bkt * BKT_CAP + lbase[bkt] + slot] =
                (unsigned int)r | ((unsigned int)(c & 255) << 16);
        }
    }
}

// ===========================================================================
// Pass B (merged hist+scan+scatter): per-bucket col histogram -> dinv,
// local scan of padded degrees, ONE global atomicAdd for the bucket base
// (CSR segments need not be globally col-ordered: start/len are packed into
// rowptr[col] = start | (paddeg/4)<<20; total padded <= 760000 < 2^20).
// Then scatter into CSR via LDS cursors and write sentinel pads.
// ===========================================================================
template <typename IdxT>
__global__ __launch_bounds__(256) void bucket_build_kernel(const unsigned int* __restrict__ binned,
                                                           const int* __restrict__ gcursor,
                                                           int* __restrict__ gbase,
                                                           float* __restrict__ dinv,
                                                           int* __restrict__ rowptr,
                                                           IdxT* __restrict__ csr) {
    __shared__ int chist[256];
    __shared__ int scn[256];
    __shared__ int ccur[256];
    __shared__ int sbase;
    const int b = blockIdx.x, t = threadIdx.x;
    chist[t] = 0;
    __syncthreads();
    const int cnt = gcursor[b];
    const unsigned int* src = binned + (size_t)b * BKT_CAP;
    for (int i = t; i < cnt; i += 256) atomicAdd(&chist[src[i] >> 16], 1);
    __syncthreads();
    const int col = b * 256 + t;
    const int valid = (col < N_NODES);
    int d = chist[t];
    if (valid) dinv[col] = rsqrtf(1.0f + (float)d);
    int pd = valid ? ((d + 3) & ~3) : 0;
    scn[t] = pd;
    __syncthreads();
    for (int off = 1; off < 256; off <<= 1) {
        int add = (t >= off) ? scn[t - off] : 0;
        __syncthreads();
        scn[t] += add;
        __syncthreads();
    }
    if (t == 255) sbase = atomicAdd(gbase, scn[255]);
    __syncthreads();
    const int start = sbase + scn[t] - pd;
    if (valid) rowptr[col] = start | ((pd >> 2) << 20);
    ccur[t] = start;
    __syncthreads();
    for (int i = t; i < cnt; i += 256) {
        unsigned int u = src[i];
        int slot = atomicAdd(&ccur[u >> 16], 1);
        csr[slot] = (IdxT)(u & 0xFFFFu);
    }
    __syncthreads();
    if (valid) {
        int cur = ccur[t];
        int endp = start + pd;
        for (int p = cur; p < endp; ++p) csr[p] = (IdxT)N_NODES;
    }
}

// ===========================================================================
// fp16 load helpers
// ===========================================================================
__device__ inline float4 load_h4(const __half* p) {
    uint2 raw = *(const uint2*)p;
    __half2 h0 = *(__half2*)&raw.x;
    __half2 h1 = *(__half2*)&raw.y;
    float2 f0 = __half22float2(h0);
    float2 f1 = __half22float2(h1);
    return make_float4(f0.x, f0.y, f1.x, f1.y);
}
__device__ inline float4 load4v(const float* p)  { return *(const float4*)(p); }
__device__ inline float4 load4v(const __half* p) { return load_h4(p); }

// unpack 8 halves (one uint4) and accumulate into a[0..7] (static indices only)
__device__ inline void acc8(const uint4& raw, float* a) {
    float2 f;
    f = __half22float2(*(const __half2*)&raw.x); a[0] += f.x; a[1] += f.y;
    f = __half22float2(*(const __half2*)&raw.y); a[2] += f.x; a[3] += f.y;
    f = __half22float2(*(const __half2*)&raw.z); a[4] += f.x; a[5] += f.y;
    f = __half22float2(*(const __half2*)&raw.w); a[6] += f.x; a[7] += f.y;
}

// ===========================================================================
// GEMM (r9-proven shape): Ht[r][c] = dinv[r] * sum_k X[r][k] * W[k][c]
// 256 threads -> 64 rows x 64 cols, thread = 4x4; W col-half (32 KB LDS)
// -> 4 blocks/CU; explicit X double-buffer prefetch. fp16 out.
// InT = float (layer 1, x) or __half (layer 2, fp16 obuf).
// ===========================================================================
template <typename InT>
__global__ __launch_bounds__(256, 4) void gemm64h_kernel(const InT* __restrict__ X,
                                                         const float* __restrict__ W,
                                                         const float* __restrict__ dinv,
                                                         __half* __restrict__ H) {
    __shared__ float Ws[128 * 64];
    const int colhalf = blockIdx.x & 1;
    const int tile    = blockIdx.x >> 1;

    for (int i = threadIdx.x; i < 2048; i += 256) {
        int k   = i >> 4;
        int cc4 = (i & 15) * 4;
        *(float4*)(Ws + k * 64 + cc4) = *(const float4*)(W + k * 128 + colhalf * 64 + cc4);
    }
    __syncthreads();

    const int rg = threadIdx.x >> 4;
    const int cg = threadIdx.x & 15;
    const int row0 = tile * 64 + rg * 4;
    const InT* x0 = X + (size_t)row0 * NFEAT;

    float acc[4][4] = {};
    float4 xc[4], xn[4];
    #pragma unroll
    for (int i = 0; i < 4; i++) xc[i] = load4v(x0 + (size_t)i * NFEAT);

    #pragma unroll 4
    for (int k = 0; k < 128; k += 4) {
        const int kn = (k + 4) & 127;
        #pragma unroll
        for (int i = 0; i < 4; i++) xn[i] = load4v(x0 + (size_t)i * NFEAT + kn);

        float4 wv[4];
        #pragma unroll
        for (int m = 0; m < 4; m++) wv[m] = *(const float4*)(Ws + (k + m) * 64 + cg * 4);

        #pragma unroll
        for (int i = 0; i < 4; i++) {
            const float xi[4] = {xc[i].x, xc[i].y, xc[i].z, xc[i].w};
            #pragma unroll
            for (int m = 0; m < 4; m++) {
                acc[i][0] += xi[m] * wv[m].x;
                acc[i][1] += xi[m] * wv[m].y;
                acc[i][2] += xi[m] * wv[m].z;
                acc[i][3] += xi[m] * wv[m].w;
            }
        }
        #pragma unroll
        for (int i = 0; i < 4; i++) xc[i] = xn[i];
    }

    #pragma unroll
    for (int i = 0; i < 4; i++) {
        float dr = dinv[row0 + i];
        __half2 p0 = __floats2half2_rn(acc[i][0] * dr, acc[i][1] * dr);
        __half2 p1 = __floats2half2_rn(acc[i][2] * dr, acc[i][3] * dr);
        uint2 pk;
        pk.x = *(unsigned int*)&p0;
        pk.y = *(unsigned int*)&p1;
        *(uint2*)(H + (size_t)(row0 + i) * NFEAT + colhalf * 64 + cg * 4) = pk;
    }
}

// ===========================================================================
// Wide gather: one wave per node; 16 B/lane (uint4 = 8 halves); wave split
// into 4 quarters of 16 lanes, quarter q takes padded-neighbor slot q of
// each group of 4 -> ONE dwordx4 load covers 4 neighbor rows per iteration.
// Quarter partial sums merge once at the end via shfl_xor(16|32). Packed
// rowptr: start = u & 0xFFFFF, padded_deg = (u>>20)<<2. Sentinel idx N_NODES
// hits the zeroed hbuf row. Layer 1: write fp16 outh. FUSE_POOL: dot Wfc,
// reduce, store nodedot[node].
// ===========================================================================
template <typename IdxT, typename IdxV, bool FUSE_POOL>
__global__ __launch_bounds__(256) void gather_w16_kernel(
        const int* __restrict__ rowptr, const IdxT* __restrict__ csr,
        const float* __restrict__ dinv, const __half* __restrict__ Ht,
        const float* __restrict__ bias, __half* __restrict__ outh,
        const float* __restrict__ Wfc, float* __restrict__ nodedot, int n) {
    int gid  = blockIdx.x * blockDim.x + threadIdx.x;
    int node = gid >> 6;
    if (node >= n) return;
    int lane = threadIdx.x & 63;
    int q    = lane >> 4;          // neighbor slot within group of 4
    int fo   = lane & 15;          // feature octet: halves [fo*8, fo*8+8)

    unsigned int u = (unsigned int)rowptr[node];
    int start = (int)(u & 0xFFFFFu);
    int pd    = (int)(u >> 20) << 2;
    int end   = start + pd;

    float a[8] = {0.f, 0.f, 0.f, 0.f, 0.f, 0.f, 0.f, 0.f};

    // self-loop: quarter 0 adds it once
    if (q == 0) {
        uint4 raw = *(const uint4*)(Ht + (size_t)node * NFEAT + fo * 8);
        acc8(raw, a);
    }

    if (start < end) {
        IdxV nxt = *(const IdxV*)(csr + start);
        for (int j = start; j < end; j += 4) {
            IdxV cur = nxt;
            int jn = j + 4;
            if (jn < end) nxt = *(const IdxV*)(csr + jn);
            int r = (q == 0) ? (int)cur.x : (q == 1) ? (int)cur.y
                  : (q == 2) ? (int)cur.z : (int)cur.w;
            uint4 raw = *(const uint4*)(Ht + (size_t)r * NFEAT + fo * 8);
            acc8(raw, a);
        }
    }

    // merge the 4 quarter partial sums (all lanes end with the full sum)
    #pragma unroll
    for (int i = 0; i < 8; i++) {
        a[i] += __shfl_xor(a[i], 16, 64);
        a[i] += __shfl_xor(a[i], 32, 64);
    }

    float di = dinv[node];
    const float4 bb0 = *(const float4*)(bias + fo * 8);
    const float4 bb1 = *(const float4*)(bias + fo * 8 + 4);
    float o0 = fmaxf(a[0] * di + bb0.x, 0.0f);
    float o1 = fmaxf(a[1] * di + bb0.y, 0.0f);
    float o2 = fmaxf(a[2] * di + bb0.z, 0.0f);
    float o3 = fmaxf(a[3] * di + bb0.w, 0.0f);
    float o4 = fmaxf(a[4] * di + bb1.x, 0.0f);
    float o5 = fmaxf(a[5] * di + bb1.y, 0.0f);
    float o6 = fmaxf(a[6] * di + bb1.z, 0.0f);
    float o7 = fmaxf(a[7] * di + bb1.w, 0.0f);

    if (!FUSE_POOL) {
        if (q == 0) {
            __half2 p0 = __floats2half2_rn(o0, o1);
            __half2 p1 = __floats2half2_rn(o2, o3);
            __half2 p2 = __floats2half2_rn(o4, o5);
            __half2 p3 = __floats2half2_rn(o6, o7);
            uint4 pk;
            pk.x = *(unsigned int*)&p0;
            pk.y = *(unsigned int*)&p1;
            pk.z = *(unsigned int*)&p2;
            pk.w = *(unsigned int*)&p3;
            *(uint4*)(outh + (size_t)node * NFEAT + fo * 8) = pk;
        }
    } else {
        const float4 wf0 = *(const float4*)(Wfc + fo * 8);
        const float4 wf1 = *(const float4*)(Wfc + fo * 8 + 4);
        float dsum = o0 * wf0.x + o1 * wf0.y + o2 * wf0.z + o3 * wf0.w
                   + o4 * wf1.x + o5 * wf1.y + o6 * wf1.z + o7 * wf1.w;
        // sum the 16 feature octets (each quarter holds all 16 -> xor within quarter)
        dsum += __shfl_xor(dsum, 1, 64);
        dsum += __shfl_xor(dsum, 2, 64);
        dsum += __shfl_xor(dsum, 4, 64);
        dsum += __shfl_xor(dsum, 8, 64);
        if (lane == 0) nodedot[node] = dsum;   // wave owns node: plain store
    }
}

// out[batch[i]] += nodedot[i] / cnt
__global__ void pool_final_kernel(const float* __restrict__ nodedot,
                                  const int* __restrict__ batch,
                                  const int* __restrict__ gcnt,
                                  float* __restrict__ out, int n) {
    int i = blockIdx.x * blockDim.x + threadIdx.x;
    if (i < n) {
        int g = batch[i];
        int c = gcnt[g];
        float cf = (float)(c > 0 ? c : 1);
        atomicAdd(&out[g], nodedot[i] / cf);
    }
}

// ===========================================================================
// Tier C fallback kernels (fp32, atomic scatter)
// ===========================================================================
__global__ void edge_deg_int_kernel(const int* __restrict__ ei, int* __restrict__ degcnt, int E) {
    int e = blockIdx.x * blockDim.x + threadIdx.x;
    if (e < E) atomicAdd(&degcnt[ei[E + e]], 1);
}

__global__ void dinv_from_int_kernel(const int* __restrict__ degcnt, float* __restrict__ dinv, int n) {
    int i = blockIdx.x * blockDim.x + threadIdx.x;
    if (i < n) dinv[i] = rsqrtf(1.0f + (float)degcnt[i]);
}

__global__ __launch_bounds__(256, 4) void gemm64f_kernel(const float* __restrict__ X,
                                                         const float* __restrict__ W,
                                                         const float* __restrict__ dinv,
                                                         float* __restrict__ H) {
    __shared__ float Ws[128 * 64];
    const int colhalf = blockIdx.x & 1;
    const int tile    = blockIdx.x >> 1;
    for (int i = threadIdx.x; i < 2048; i += 256) {
        int k   = i >> 4;
        int cc4 = (i & 15) * 4;
        *(float4*)(Ws + k * 64 + cc4) = *(const float4*)(W + k * 128 + colhalf * 64 + cc4);
    }
    __syncthreads();
    const int rg = threadIdx.x >> 4;
    const int cg = threadIdx.x & 15;
    const int row0 = tile * 64 + rg * 4;
    const float* x0 = X + (size_t)row0 * NFEAT;
    float acc[4][4] = {};
    #pragma unroll 4
    for (int k = 0; k < 128; k += 4) {
        float4 xv[4];
        float4 wv[4];
        #pragma unroll
        for (int i = 0; i < 4; i++) xv[i] = *(const float4*)(x0 + (size_t)i * NFEAT + k);
        #pragma unroll
        for (int m = 0; m < 4; m++) wv[m] = *(const float4*)(Ws + (k + m) * 64 + cg * 4);
        #pragma unroll
        for (int i = 0; i < 4; i++) {
            const float xi[4] = {xv[i].x, xv[i].y, xv[i].z, xv[i].w};
            #pragma unroll
            for (int m = 0; m < 4; m++) {
                acc[i][0] += xi[m] * wv[m].x;
                acc[i][1] += xi[m] * wv[m].y;
                acc[i][2] += xi[m] * wv[m].z;
                acc[i][3] += xi[m] * wv[m].w;
            }
        }
    }
    #pragma unroll
    for (int i = 0; i < 4; i++) {
        float dr = dinv[row0 + i];
        float4 o = {acc[i][0] * dr, acc[i][1] * dr, acc[i][2] * dr, acc[i][3] * dr};
        *(float4*)(H + (size_t)(row0 + i) * NFEAT + cg * 4 + colhalf * 64) = o;
    }
}

__global__ __launch_bounds__(256) void edge_scatter_kernel(const int* __restrict__ ei,
                                                           const float* __restrict__ dinv,
                                                           const float* __restrict__ H,
                                                           float* __restrict__ agg,
                                                           int E) {
    long long gid = (long long)blockIdx.x * blockDim.x + threadIdx.x;
    int e = (int)(gid >> 5);
    if (e >= E) return;
    int c4 = ((int)gid & 31) * 4;
    int r = ei[e];
    int c = ei[E + e];
    float norm = dinv[c];
    const float4 hv = *(const float4*)(H + (size_t)r * NFEAT + c4);
    float* dst = agg + (size_t)c * NFEAT + c4;
    atomicAdd(dst + 0, hv.x * norm);
    atomicAdd(dst + 1, hv.y * norm);
    atomicAdd(dst + 2, hv.z * norm);
    atomicAdd(dst + 3, hv.w * norm);
}

__global__ void post_kernel(float* __restrict__ agg, const float* __restrict__ H,
                            const float* __restrict__ dinv, const float* __restrict__ b,
                            int n) {
    int gid = blockIdx.x * blockDim.x + threadIdx.x;
    if (gid >= n * 32) return;
    int node = gid >> 5;
    int c4 = (gid & 31) * 4;
    float s = dinv[node];
    float4 a  = *(float4*)(agg + (size_t)gid * 4);
    float4 hv = *(const float4*)(H + (size_t)gid * 4);
    float4 bb = *(const float4*)(b + c4);
    float4 o;
    o.x = fmaxf(a.x + hv.x * s + bb.x, 0.0f);
    o.y = fmaxf(a.y + hv.y * s + bb.y, 0.0f);
    o.z = fmaxf(a.z + hv.z * s + bb.z, 0.0f);
    o.w = fmaxf(a.w + hv.w * s + bb.w, 0.0f);
    *(float4*)(agg + (size_t)gid * 4) = o;
}

__global__ __launch_bounds__(128) void pool_fc_kernel(const float* __restrict__ H,
                                                      const int* __restrict__ batch,
                                                      const float* __restrict__ Wfc,
                                                      const float* __restrict__ bfc,
                                                      float* __restrict__ out, int n) {
    int g = blockIdx.x;
    int tid = threadIdx.x;
    int lo = 0, hi = n;
    while (lo < hi) { int mid = (lo + hi) >> 1; if (batch[mid] < g) lo = mid + 1; else hi = mid; }
    int start = lo;
    hi = n;
    while (lo < hi) { int mid = (lo + hi) >> 1; if (batch[mid] < g + 1) lo = mid + 1; else hi = mid; }
    int end = lo;
    float acc = 0.0f;
    for (int nd = start; nd < end; ++nd) acc += H[(size_t)nd * NFEAT + tid];
    float cnt = (float)((end - start) > 0 ? (end - start) : 1);
    float v = (acc / cnt) * Wfc[tid];
    __shared__ float red[128];
    red[tid] = v;
    __syncthreads();
    #pragma unroll
    for (int s = 64; s > 0; s >>= 1) {
        if (tid < s) red[tid] += red[tid + s];
        __syncthreads();
    }
    if (tid == 0) out[g] = red[0] + bfc[0];
}

// ===========================================================================
// Host launcher — main path: ushort CSR, fp16 hbuf + fp16 obuf
// ===========================================================================
static void run_csr_path(const float* x, const int* ei, const int* batch,
                         const float* W1, const float* b1, const float* W2,
                         const float* b2, const float* Wfc, const float* bfc,
                         float* out, void* d_ws, hipStream_t stream) {
    typedef unsigned short IdxT;
    typedef ushort4 IdxV;
    char* ws = (char*)d_ws;
    const size_t hbytes = (size_t)(N_NODES + 1) * NFEAT * sizeof(__half);  // +1 sentinel row
    const size_t obytes = (size_t)N_NODES * NFEAT * sizeof(__half);
    __half* hbuf  = (__half*)ws;
    __half* obuf  = (__half*)(ws + hbytes);
    IdxT*   csr   = (IdxT*)(ws + hbytes + obytes);
    char*   p     = ws + hbytes + obytes + ((size_t)EPAD_MAX * sizeof(IdxT) + 15) / 16 * 16;
    int*    rowptr = (int*)p;                p += ((size_t)(N_NODES + 1) * 4 + 15) / 16 * 16;
    float*  dinv   = (float*)p;              p += ((size_t)N_NODES * 4 + 15) / 16 * 16;
    int*    gcnt   = (int*)p;                // 512 ints (live through pool_final)

    // CSR-build scratch overlapping obuf (dead until gather1 writes it)
    unsigned int* binned = (unsigned int*)obuf;        // NBKT*BKT_CAP u32 = 5.14 MB < 10.2 MB
    int* gcursor = (int*)(binned + (size_t)NBKT * BKT_CAP);  // NBKT+1 ints ([NBKT]=gbase)
    float* nodedot = (float*)(p + (((size_t)N_GRAPHS * 4 + 15) / 16 * 16));

    // ---- init + CSR build (binned counting sort, atomic bucket bases) ----
    init_misc_kernel<<<1, 256, 0, stream>>>(gcursor, gcnt, out, bfc,
                                            hbuf + (size_t)N_NODES * NFEAT);
    batch_hist_kernel<<<SCAN_NB, 256, 0, stream>>>(batch, gcnt, N_NODES);
    bin_kernel<<<NBLK_A, 256, 0, stream>>>(ei, gcursor, binned);
    bucket_build_kernel<IdxT><<<NBKT, 256, 0, stream>>>(binned, gcursor, gcursor + NBKT,
                                                        dinv, rowptr, csr);

    // ---- layer 1 ----
    gemm64h_kernel<float><<<(N_NODES / 64) * 2, 256, 0, stream>>>(x, W1, dinv, hbuf);
    gather_w16_kernel<IdxT, IdxV, false><<<(N_NODES * 64) / 256, 256, 0, stream>>>(
        rowptr, csr, dinv, hbuf, b1, obuf, nullptr, nullptr, N_NODES);

    // ---- layer 2 ----
    gemm64h_kernel<__half><<<(N_NODES / 64) * 2, 256, 0, stream>>>(obuf, W2, dinv, hbuf);
    gather_w16_kernel<IdxT, IdxV, true><<<(N_NODES * 64) / 256, 256, 0, stream>>>(
        rowptr, csr, dinv, hbuf, b2, nullptr, Wfc, nodedot, N_NODES);

    // ---- final pool ----
    pool_final_kernel<<<SCAN_NB, 256, 0, stream>>>(nodedot, batch, gcnt, out, N_NODES);
}

extern "C" void kernel_launch(void* const* d_in, const int* in_sizes, int n_in,
                              void* d_out, int out_size, void* d_ws, size_t ws_size,
                              hipStream_t stream) {
    const float* x     = (const float*)d_in[0];
    const int*   ei    = (const int*)  d_in[1];
    const int*   batch = (const int*)  d_in[2];
    const float* W1    = (const float*)d_in[3];
    const float* b1    = (const float*)d_in[4];
    const float* W2    = (const float*)d_in[5];
    const float* b2    = (const float*)d_in[6];
    const float* Wfc   = (const float*)d_in[7];
    const float* bfc   = (const float*)d_in[8];
    float* out = (float*)d_out;

    const size_t hbytes = (size_t)(N_NODES + 1) * NFEAT * sizeof(__half);
    const size_t obytes = (size_t)N_NODES * NFEAT * sizeof(__half);
    const size_t tail   = ((size_t)(N_NODES + 1) * 4 + 15) / 16 * 16
                        + ((size_t)N_NODES * 4 + 15) / 16 * 16
                        + (((size_t)N_GRAPHS * 4 + 15) / 16 * 16)
                        + (size_t)N_NODES * 4;                       // nodedot
    const size_t need = hbytes + obytes + ((size_t)EPAD_MAX * 2 + 15) / 16 * 16 + tail;

    if (ws_size >= need) {
        run_csr_path(x, ei, batch, W1, b1, W2, b2, Wfc, bfc, out, d_ws, stream);
    } else {
        // Tier C: fp32 atomic-scatter fallback
        float* ws   = (float*)d_ws;
        int*   degc = (int*)ws;
        float* dinv = ws + N_NODES;
        float* hbuf = ws + 2 * N_NODES;
        float* agg  = hbuf + (size_t)N_NODES * NFEAT;
        const size_t fb2 = (size_t)N_NODES * NFEAT * sizeof(float);

        hipMemsetAsync(degc, 0, (size_t)N_NODES * sizeof(int), stream);
        edge_deg_int_kernel<<<N_EDGES / 256, 256, 0, stream>>>(ei, degc, N_EDGES);
        dinv_from_int_kernel<<<SCAN_NB, 256, 0, stream>>>(degc, dinv, N_NODES);

        hipMemsetAsync(agg, 0, fb2, stream);
        gemm64f_kernel<<<(N_NODES / 64) * 2, 256, 0, stream>>>(x, W1, dinv, hbuf);
        edge_scatter_kernel<<<(N_EDGES * 32) / 256, 256, 0, stream>>>(ei, dinv, hbuf, agg, N_EDGES);
        post_kernel<<<(N_NODES * 32) / 256, 256, 0, stream>>>(agg, hbuf, dinv, b1, N_NODES);

        gemm64f_kernel<<<(N_NODES / 64) * 2, 256, 0, stream>>>(agg, W2, dinv, hbuf);
        hipMemsetAsync(agg, 0, fb2, stream);
        edge_scatter_kernel<<<(N_EDGES * 32) / 256, 256, 0, stream>>>(ei, dinv, hbuf, agg, N_EDGES);
        post_kernel<<<(N_NODES * 32) / 256, 256, 0, stream>>>(agg, hbuf, dinv, b2, N_NODES);

        pool_fc_kernel<<<N_GRAPHS, 128, 0, stream>>>(agg, batch, Wfc, bfc, out, N_NODES);
    }
}